// Round 1
// baseline (15365.813 us; speedup 1.0000x reference)
//
#include <hip/hip_runtime.h>

// Conv3D: x (8,3,16,112,112) f32, w (64,3,5,7,7), bias (64,)
// stride (1,2,2), pad ((2,2),(3,3),(3,3)) -> out (8,64,16,56,56)

#define NB   8
#define CI   3
#define DI   16
#define HI   112
#define WI   112
#define CO   64
#define KD   5
#define KH   7
#define KW   7
#define PD   2
#define PH   3
#define PW   3
#define DO   16
#define HO   56
#define WO   56
#define KTOT (CI*KD*KH*KW)   // 735
#define OT   8               // output channels per thread

__launch_bounds__(256, 2)
__global__ void conv3d_direct(const float* __restrict__ x,
                              const float* __restrict__ wgt,
                              const float* __restrict__ bias,
                              float* __restrict__ out) {
    // Stage this block's 8 output-channel weight vectors into LDS,
    // transposed to [k][8] so the inner loop reads 8 contiguous floats
    // at a wave-uniform address (broadcast, no bank conflicts).
    __shared__ float lds_w[KTOT * OT];  // 23520 B
    const int tid = threadIdx.x;
    const int o0  = blockIdx.y * OT;
    const float* wsrc = wgt + (size_t)o0 * KTOT;
    for (int idx = tid; idx < KTOT * OT; idx += 256) {
        const int i = idx & (OT - 1);
        const int k = idx >> 3;
        lds_w[idx] = wsrc[(size_t)i * KTOT + k];
    }
    __syncthreads();

    // One output voxel per thread; consecutive lanes -> consecutive wo.
    const int s  = blockIdx.x * 256 + tid;        // 0 .. 401407
    const int wo = s % WO;
    int t        = s / WO;
    const int ho = t % HO;
    t /= HO;
    const int dd = t % DO;
    const int n  = t / DO;

    float acc[OT];
    #pragma unroll
    for (int i = 0; i < OT; ++i) acc[i] = bias[o0 + i];

    const float* xn   = x + (size_t)n * (CI * DI * HI * WI);
    const int wbase   = 2 * wo - PW;
    const int hbase   = 2 * ho - PH;
    const int dbase   = dd - PD;

    #pragma unroll 1
    for (int c = 0; c < CI; ++c) {
        const float* xc = xn + c * (DI * HI * WI);
        #pragma unroll 1
        for (int kd = 0; kd < KD; ++kd) {
            const int  din = dbase + kd;
            const bool dok = (unsigned)din < (unsigned)DI;
            const float* xd = xc + din * (HI * WI);
            const int kbase = (c * KD + kd) * (KH * KW);
            #pragma unroll
            for (int kh = 0; kh < KH; ++kh) {
                const int  hin = hbase + kh;
                const bool hok = dok && ((unsigned)hin < (unsigned)HI);
                const float* xh = xd + hin * WI + wbase;
                #pragma unroll
                for (int kw = 0; kw < KW; ++kw) {
                    const int win = wbase + kw;
                    const float xv =
                        (hok && ((unsigned)win < (unsigned)WI)) ? xh[kw] : 0.0f;
                    const int kidx = (kbase + kh * KW + kw) * OT;
                    const float4 wa = *reinterpret_cast<const float4*>(&lds_w[kidx]);
                    const float4 wb = *reinterpret_cast<const float4*>(&lds_w[kidx + 4]);
                    acc[0] = fmaf(xv, wa.x, acc[0]);
                    acc[1] = fmaf(xv, wa.y, acc[1]);
                    acc[2] = fmaf(xv, wa.z, acc[2]);
                    acc[3] = fmaf(xv, wa.w, acc[3]);
                    acc[4] = fmaf(xv, wb.x, acc[4]);
                    acc[5] = fmaf(xv, wb.y, acc[5]);
                    acc[6] = fmaf(xv, wb.z, acc[6]);
                    acc[7] = fmaf(xv, wb.w, acc[7]);
                }
            }
        }
    }

    float* op = out + ((((size_t)n * CO + o0) * DO + dd) * HO + ho) * WO + wo;
    #pragma unroll
    for (int i = 0; i < OT; ++i)
        op[(size_t)i * (DO * HO * WO)] = acc[i];
}

extern "C" void kernel_launch(void* const* d_in, const int* in_sizes, int n_in,
                              void* d_out, int out_size, void* d_ws, size_t ws_size,
                              hipStream_t stream) {
    const float* x    = (const float*)d_in[0];
    const float* wgt  = (const float*)d_in[1];
    const float* bias = (const float*)d_in[2];
    float* out        = (float*)d_out;

    // spatial outputs: 8*16*56*56 = 401408 = 1568 * 256
    dim3 grid(1568, CO / OT, 1);
    dim3 block(256, 1, 1);
    hipLaunchKernelGGL(conv3d_direct, grid, block, 0, stream, x, wgt, bias, out);
}

// Round 2
// 236.568 us; speedup vs baseline: 64.9530x; 64.9530x over previous
//
#include <hip/hip_runtime.h>

// Conv3D as implicit GEMM on bf16 MFMA.
// x (8,3,16,112,112) f32, w (64,3,5,7,7), bias (64,), stride (1,2,2),
// pad ((2,2),(3,3),(3,3)) -> out (8,64,16,56,56) f32.
// GEMM: M = CO = 64 (A = weights), N = spatial = 401408 (B = im2col patches),
// K = 735 padded to 736 = 23 chunks of 32. mfma_f32_16x16x32_bf16.

typedef __attribute__((ext_vector_type(8))) short short8;
typedef __attribute__((ext_vector_type(4))) float f32x4;

#define CI 3
#define DI 16
#define HI 112
#define WI 112
#define CO 64
#define KD 5
#define KH 7
#define KW 7
#define DO_ 16
#define HO 56
#define WO 56
#define KTOT 735            // 3*5*7*7
#define KPAD 736            // 23*32
#define NCHUNK 23
#define MT 128              // spatial positions per block
#define HW_IN  (HI*WI)      // 12544
#define DHW_IN (DI*HW_IN)   // 200704
#define CDHW_IN (CI*DHW_IN) // 602112
#define HWO  (HO*WO)        // 3136
#define DHWO (DO_*HWO)      // 50176
#define SPATIAL (8*DHWO)    // 401408

__device__ __forceinline__ unsigned short f2bf(float f) {
    unsigned u = __float_as_uint(f);
    return (unsigned short)((u + 0x7FFFu + ((u >> 16) & 1u)) >> 16);
}

__launch_bounds__(256, 3)
__global__ void conv3d_mfma(const float* __restrict__ x,
                            const float* __restrict__ wgt,
                            const float* __restrict__ bias,
                            float* __restrict__ out) {
    // packed tap table: off(19b) | kd<<19 (3b) | kh<<22 (3b) | kw<<25
    __shared__ __align__(16) unsigned tab[KPAD];
    // fragment-ready B (x patches): octet o = nf*64 + lane holds
    // B[k=(lane>>4)*8+j][sp=nf*16+(lane&15)]
    __shared__ short8 xfrag[512];   // 8 KB

    const int tid   = threadIdx.x;
    const int ntile = blockIdx.x;
    const int lane  = tid & 63;
    const int wid   = tid >> 6;
    const int kgrp  = (lane >> 4);          // 0..3

    // ---- build tap table (once per block) ----
    for (int k = tid; k < KPAD; k += 256) {
        int kk = min(k, KTOT - 1);          // k=735 duplicates 734; weight=0 kills it
        int c  = kk / (KD * KH * KW);
        int r  = kk - c * (KD * KH * KW);
        int kd = r / (KH * KW);
        int r2 = r - kd * (KH * KW);
        int kh = r2 / KW;
        int kw = r2 - kh * KW;
        unsigned off = (unsigned)(c * DHW_IN + kd * HW_IN + kh * WI + kw);
        tab[k] = off | ((unsigned)kd << 19) | ((unsigned)kh << 22) | ((unsigned)kw << 25);
    }

    // ---- spatial decode for this thread's two x-octets ----
    const int sp1 = (wid << 4) + (lane & 15);
    int sb0, sb1, dB0, dB1, hB0, hB1, wB0, wB1;
    {
        int s = ntile * MT + sp1;
        int wo = s % WO; int t1 = s / WO;
        int ho = t1 % HO; int t2 = t1 / HO;
        int dd = t2 % DO_; int n = t2 / DO_;
        dB0 = dd - 2; hB0 = 2 * ho - 3; wB0 = 2 * wo - 3;
        sb0 = n * CDHW_IN + dB0 * HW_IN + hB0 * WI + wB0;
    }
    {
        int s = ntile * MT + sp1 + 64;
        int wo = s % WO; int t1 = s / WO;
        int ho = t1 % HO; int t2 = t1 / HO;
        int dd = t2 % DO_; int n = t2 / DO_;
        dB1 = dd - 2; hB1 = 2 * ho - 3; wB1 = 2 * wo - 3;
        sb1 = n * CDHW_IN + dB1 * HW_IN + hB1 * WI + wB1;
    }

    // ---- this thread's A (weight) fragment source: exactly its compute frag ----
    const int co_w = (wid << 4) + (lane & 15);
    const float* wrow = wgt + co_w * KTOT;

    // ---- acc init with bias (C/D: row = (lane>>4)*4 + reg -> co) ----
    const int co0 = wid * 16 + ((lane >> 4) << 2);
    f32x4 bv;
    bv[0] = bias[co0]; bv[1] = bias[co0 + 1];
    bv[2] = bias[co0 + 2]; bv[3] = bias[co0 + 3];
    f32x4 acc[8];
    #pragma unroll
    for (int nf = 0; nf < 8; ++nf) acc[nf] = bv;

    __syncthreads();    // tab ready

    for (int ch = 0; ch < NCHUNK; ++ch) {
        const int k0 = ch * 32 + kgrp * 8;
        // ---- gather A fragment (weights) straight to registers ----
        short8 aw;
        #pragma unroll
        for (int j = 0; j < 8; ++j) {
            int k = k0 + j;
            float v = (k < KTOT) ? wrow[k] : 0.0f;
            aw[j] = (short)f2bf(v);
        }
        // ---- gather 2 x-octets into fragment-ready LDS ----
        uint4 ta = *reinterpret_cast<const uint4*>(&tab[k0]);
        uint4 tb = *reinterpret_cast<const uint4*>(&tab[k0 + 4]);
        unsigned ee[8] = {ta.x, ta.y, ta.z, ta.w, tb.x, tb.y, tb.z, tb.w};
        {
            short8 r;
            #pragma unroll
            for (int j = 0; j < 8; ++j) {
                unsigned e = ee[j];
                int off = (int)(e & 0x7FFFFu);
                int kd = (int)((e >> 19) & 7u);
                int kh = (int)((e >> 22) & 7u);
                int kw = (int)(e >> 25);
                bool ok = ((unsigned)(dB0 + kd) < (unsigned)DI) &
                          ((unsigned)(hB0 + kh) < (unsigned)HI) &
                          ((unsigned)(wB0 + kw) < (unsigned)WI);
                float v = ok ? x[sb0 + off] : 0.0f;
                r[j] = (short)f2bf(v);
            }
            xfrag[tid] = r;
        }
        {
            short8 r;
            #pragma unroll
            for (int j = 0; j < 8; ++j) {
                unsigned e = ee[j];
                int off = (int)(e & 0x7FFFFu);
                int kd = (int)((e >> 19) & 7u);
                int kh = (int)((e >> 22) & 7u);
                int kw = (int)(e >> 25);
                bool ok = ((unsigned)(dB1 + kd) < (unsigned)DI) &
                          ((unsigned)(hB1 + kh) < (unsigned)HI) &
                          ((unsigned)(wB1 + kw) < (unsigned)WI);
                float v = ok ? x[sb1 + off] : 0.0f;
                r[j] = (short)f2bf(v);
            }
            xfrag[256 + tid] = r;
        }
        __syncthreads();
        // ---- compute: 8 MFMAs (this wave's co-frag x 8 spatial frags) ----
        #pragma unroll
        for (int nf = 0; nf < 8; ++nf) {
            short8 bx = xfrag[nf * 64 + lane];
            acc[nf] = __builtin_amdgcn_mfma_f32_16x16x32_bf16(aw, bx, acc[nf], 0, 0, 0);
        }
        __syncthreads();
    }

    // ---- store: col = lane&15 -> spatial (quarter-wave coalesced) ----
    const int l15 = lane & 15;
    #pragma unroll
    for (int nf = 0; nf < 8; ++nf) {
        int s = ntile * MT + nf * 16 + l15;
        int wo = s % WO; int t1 = s / WO;
        int ho = t1 % HO; int t2 = t1 / HO;
        int dd = t2 % DO_; int n = t2 / DO_;
        float* op = out + (((size_t)(n * CO + co0) * DO_ + dd) * HWO + ho * WO + wo);
        #pragma unroll
        for (int r = 0; r < 4; ++r)
            op[(size_t)r * DHWO] = acc[nf][r];
    }
}

extern "C" void kernel_launch(void* const* d_in, const int* in_sizes, int n_in,
                              void* d_out, int out_size, void* d_ws, size_t ws_size,
                              hipStream_t stream) {
    const float* x    = (const float*)d_in[0];
    const float* wgt  = (const float*)d_in[1];
    const float* bias = (const float*)d_in[2];
    float* out        = (float*)d_out;

    dim3 grid(SPATIAL / MT, 1, 1);   // 3136 blocks
    dim3 block(256, 1, 1);
    hipLaunchKernelGGL(conv3d_mfma, grid, block, 0, stream, x, wgt, bias, out);
}

// Round 3
// 140.382 us; speedup vs baseline: 109.4568x; 1.6852x over previous
//
#include <hip/hip_runtime.h>

// Conv3D implicit GEMM, round 3: LDS-staged x (bf16, padded), K re-packed to
// 8-slot (c,kd,kh) rows, weights pre-converted to fragment-ready bf16 in d_ws.
// x (8,3,16,112,112) f32, w (64,3,5,7,7), bias (64,) -> out (8,64,16,56,56) f32
// stride (1,2,2), pad ((2,2),(3,3),(3,3)).

typedef __attribute__((ext_vector_type(8))) short short8;
typedef __attribute__((ext_vector_type(4))) float f32x4;

#define CI 3
#define DI 16
#define HI 112
#define WI 112
#define CO 64
#define KD 5
#define KH 7
#define KW 7
#define DO_ 16
#define HO 56
#define WO 56
#define HW_IN  (HI*WI)      // 12544
#define HWO  (HO*WO)        // 3136
#define DHWO (DO_*HWO)      // 50176

#define NROW  105           // (c,kd,kh) rows
#define NROWP 108           // padded: 27 chunks * 4 rows
#define NCH   27
#define TH    4             // ho rows per block
#define NF    7             // spatial frags per wave (112 sp / 16)
#define LROWS (CI*KD*(2*TH+5))  // 3*5*13 = 195 staged rows
#define LW    120           // padded row width in bf16 slots (win -3..116)

__device__ __forceinline__ unsigned short f2bf(float f) {
    unsigned u = __float_as_uint(f);
    return (unsigned short)((u + 0x7FFFu + ((u >> 16) & 1u)) >> 16);
}

// ---- prep: weights -> fragment-ready bf16 wbuf[ch][fa][lane] (short8) ----
// lane -> (kgrp = lane>>4, l15 = lane&15); element: co = fa*16+l15,
// k' = ch*32 + kgrp*8 + j, row r = ch*4+kgrp -> (c,kd,kh), kw = j (j=7 -> 0).
__global__ void prep_weights(const float* __restrict__ wgt, short8* __restrict__ wbuf) {
    const int t    = blockIdx.x * 64 + threadIdx.x;   // 27*4*64 = 6912
    const int lane = t & 63;
    const int cf   = t >> 6;           // ch*4 + fa
    const int ch   = cf >> 2;
    const int fa   = cf & 3;
    const int l15  = lane & 15;
    const int kgrp = lane >> 4;
    const int co   = fa * 16 + l15;
    const int r    = ch * 4 + kgrp;
    const int rc   = (r < NROW) ? r : (NROW - 1);
    const int c    = rc / 35;
    const int kd   = (rc / 7) % 5;
    const int kh   = rc % 7;
    const float* wsrc = wgt + (((co * CI + c) * KD + kd) * KH + kh) * KW;
    short8 v;
    #pragma unroll
    for (int j = 0; j < 8; ++j) {
        float w = (r < NROW && j < KW) ? wsrc[j] : 0.0f;
        v[j] = (short)f2bf(w);
    }
    wbuf[(size_t)cf * 64 + lane] = v;
}

__launch_bounds__(256, 3)
__global__ void conv3d_mfma2(const float* __restrict__ x,
                             const short8* __restrict__ wbuf,
                             const float* __restrict__ bias,
                             float* __restrict__ out) {
    __shared__ unsigned short xl[LROWS * LW];   // 46800 B, bf16, zero-padded
    __shared__ int rowg[LROWS];                 // global row offset or -1
    __shared__ unsigned short tabr[NROWP];      // row -> lds short-index base

    const int tid = threadIdx.x;
    int b = blockIdx.x;
    const int ht = b % (HO / TH);  b /= (HO / TH);
    const int dd = b % DO_;
    const int n  = b / DO_;
    const int ho0 = ht * TH;

    // ---- per-row tables ----
    if (tid < LROWS) {
        const int rl = tid % 13;
        const int t2 = tid / 13;           // c*5 + kd
        const int kd = t2 % 5;
        const int c  = t2 / 5;
        const int din = dd - 2 + kd;
        const int hin = 2 * ho0 - 3 + rl;
        const bool ok = ((unsigned)din < (unsigned)DI) && ((unsigned)hin < (unsigned)HI);
        rowg[tid] = ok ? ((n * CI + c) * DI + din) * HW_IN + hin * WI : -1;
    }
    if (tid < NROWP) {
        const int rc = (tid < NROW) ? tid : (NROW - 1);
        const int c  = rc / 35;
        const int kd = (rc / 7) % 5;
        const int kh = rc % 7;
        tabr[tid] = (unsigned short)((((c * 5 + kd) * 13) + kh) * LW);
    }
    __syncthreads();

    // ---- stage x -> LDS bf16 with zero padding ----
    for (int idx = tid; idx < LROWS * LW; idx += 256) {
        const int row  = idx / LW;
        const int slot = idx - row * LW;
        const int base = rowg[row];
        const int w    = slot - 3;
        float v = 0.0f;
        if (base >= 0 && (unsigned)w < (unsigned)WI) v = x[base + w];
        xl[idx] = f2bf(v);
    }

    // ---- per-lane geometry ----
    const int lane  = tid & 63;
    const int wid   = tid >> 6;
    const int waveM = wid & 1;      // co half
    const int waveN = wid >> 1;     // sp half
    const int l15   = lane & 15;
    const int kgrp  = lane >> 4;

    int bidx[NF];
    #pragma unroll
    for (int f = 0; f < NF; ++f) {
        const int sp  = waveN * 112 + f * 16 + l15;
        const int hoL = sp / 56;
        const int wo  = sp - hoL * 56;
        bidx[f] = hoL * 2 * LW + 2 * wo;    // even short-index offset
    }

    // ---- acc init with bias (C/D: co = waveM*32 + a*16 + kgrp*4 + reg) ----
    const int cobase = waveM * 32 + kgrp * 4;
    f32x4 bv0, bv1;
    #pragma unroll
    for (int r = 0; r < 4; ++r) {
        bv0[r] = bias[cobase + r];
        bv1[r] = bias[cobase + 16 + r];
    }
    f32x4 acc[2][NF];
    #pragma unroll
    for (int f = 0; f < NF; ++f) { acc[0][f] = bv0; acc[1][f] = bv1; }

    const short8* wb = wbuf + (size_t)(waveM * 2) * 64 + lane;

    __syncthreads();

    // ---- K loop: zero barriers, pure compute ----
    for (int ch = 0; ch < NCH; ++ch) {
        const short8 a0 = wb[ch * 256];
        const short8 a1 = wb[ch * 256 + 64];
        const int tb = (int)tabr[ch * 4 + kgrp];
        #pragma unroll
        for (int f = 0; f < NF; ++f) {
            const unsigned* p = reinterpret_cast<const unsigned*>(&xl[tb + bidx[f]]);
            union { unsigned u[4]; short8 s; } bx;
            bx.u[0] = p[0]; bx.u[1] = p[1]; bx.u[2] = p[2]; bx.u[3] = p[3];
            acc[0][f] = __builtin_amdgcn_mfma_f32_16x16x32_bf16(a0, bx.s, acc[0][f], 0, 0, 0);
            acc[1][f] = __builtin_amdgcn_mfma_f32_16x16x32_bf16(a1, bx.s, acc[1][f], 0, 0, 0);
        }
    }

    // ---- store ----
    #pragma unroll
    for (int f = 0; f < NF; ++f) {
        const int sp  = waveN * 112 + f * 16 + l15;
        const int hoL = sp / 56;
        const int wo  = sp - hoL * 56;
        const int ho  = ho0 + hoL;
        #pragma unroll
        for (int a = 0; a < 2; ++a) {
            const int co = cobase + a * 16;
            float* op = out + (((size_t)(n * CO + co) * DO_ + dd) * HO + ho) * WO + wo;
            #pragma unroll
            for (int r = 0; r < 4; ++r)
                op[(size_t)r * DHWO] = acc[a][f][r];
        }
    }
}

extern "C" void kernel_launch(void* const* d_in, const int* in_sizes, int n_in,
                              void* d_out, int out_size, void* d_ws, size_t ws_size,
                              hipStream_t stream) {
    const float* x    = (const float*)d_in[0];
    const float* wgt  = (const float*)d_in[1];
    const float* bias = (const float*)d_in[2];
    float* out        = (float*)d_out;
    short8* wbuf      = (short8*)d_ws;   // needs 27*4*64*16 = 110592 B

    hipLaunchKernelGGL(prep_weights, dim3(NCH * 4, 1, 1), dim3(64, 1, 1), 0, stream,
                       wgt, wbuf);

    // grid: 8 n * 16 dd * 14 ho-tiles = 1792 blocks
    dim3 grid(8 * DO_ * (HO / TH), 1, 1);
    hipLaunchKernelGGL(conv3d_mfma2, grid, dim3(256, 1, 1), 0, stream,
                       x, wbuf, bias, out);
}

// Round 4
// 92.010 us; speedup vs baseline: 167.0008x; 1.5257x over previous
//
#include <hip/hip_runtime.h>

// Conv3D implicit GEMM, round 4: ma=4 register blocking (wave = 64co x 112sp),
// TD=2 dd-pairing, packed cvt_pk staging, double-buffered weight frags.
// x (8,3,16,112,112) f32, w (64,3,5,7,7), bias (64,) -> out (8,64,16,56,56) f32

typedef __attribute__((ext_vector_type(8))) short short8;
typedef __attribute__((ext_vector_type(4))) float f32x4;

#define CI 3
#define DI 16
#define HI 112
#define WI 112
#define CO 64
#define KD 5
#define KH 7
#define KW 7
#define DO_ 16
#define HO 56
#define WO 56
#define HW_IN 12544
#define HWO 3136
#define DHWO 50176

#define NROW 105            // (c,kd,kh) rows
#define NROWP 108
#define NCH 27
#define TH 4                // ho rows per block
#define NF 7                // 112 spatial / 16 per wave
#define NPL 6               // staged d-planes per c (KD + TD - 1)
#define LR 13               // staged h-rows per plane (2*TH + KH - 2)
#define LROWS (CI*NPL*LR)   // 234
#define LW 128              // shorts per staged row (slots 0..127, win = slot-3)

__device__ __forceinline__ unsigned short f2bf(float f) {
    unsigned u = __float_as_uint(f);
    return (unsigned short)((u + 0x7FFFu + ((u >> 16) & 1u)) >> 16);
}

// weights -> fragment-ready bf16: wbuf[(ch*4+a)*64 + lane] = short8,
// element j: co = a*16 + (lane&15), row r = ch*4 + (lane>>4) -> (c,kd,kh), kw = j.
__global__ void prep_weights(const float* __restrict__ wgt, short8* __restrict__ wbuf) {
    const int t    = blockIdx.x * 64 + threadIdx.x;   // 27*4*64 = 6912
    const int lane = t & 63;
    const int cf   = t >> 6;
    const int ch   = cf >> 2;
    const int a    = cf & 3;
    const int l15  = lane & 15;
    const int kgrp = lane >> 4;
    const int co   = a * 16 + l15;
    const int r    = ch * 4 + kgrp;
    const int rc   = (r < NROW) ? r : (NROW - 1);
    const int c    = rc / 35;
    const int kd   = (rc / 7) % 5;
    const int kh   = rc % 7;
    const float* wsrc = wgt + (((co * CI + c) * KD + kd) * KH + kh) * KW;
    short8 v;
    #pragma unroll
    for (int j = 0; j < 8; ++j) {
        float w = (r < NROW && j < KW) ? wsrc[j] : 0.0f;
        v[j] = (short)f2bf(w);
    }
    wbuf[(size_t)cf * 64 + lane] = v;
}

__launch_bounds__(256, 2)
__global__ void conv3d_mfma3(const float* __restrict__ x,
                             const short8* __restrict__ wbuf,
                             const float* __restrict__ bias,
                             float* __restrict__ out) {
    __shared__ unsigned short xl[LROWS * LW];   // 59904 B
    __shared__ int rowg[LROWS];
    __shared__ unsigned short tabr[NROWP];

    const int tid = threadIdx.x;
    int b = blockIdx.x;
    const int ht  = b % 14;  b /= 14;
    const int ddp = b % 8;
    const int n   = b / 8;
    const int ho0 = ht * TH;
    const int dd0 = ddp * 2;

    // per-row global bases; plane p covers din = dd0 - 2 + p (p = kd + dd_local)
    if (tid < LROWS) {
        const int c   = tid / (NPL * LR);
        const int rem = tid - c * (NPL * LR);
        const int p   = rem / LR;
        const int rl  = rem - p * LR;
        const int din = dd0 - 2 + p;
        const int hin = 2 * ho0 - 3 + rl;
        const bool ok = ((unsigned)din < (unsigned)DI) && ((unsigned)hin < (unsigned)HI);
        rowg[tid] = ok ? ((n * CI + c) * DI + din) * HW_IN + hin * WI : -1;
    }
    // chunk-row -> LDS short-index base (dd_local = 0)
    if (tid < NROWP) {
        const int rc = (tid < NROW) ? tid : (NROW - 1);
        const int c  = rc / 35;
        const int kd = (rc / 7) % 5;
        const int kh = rc % 7;
        tabr[tid] = (unsigned short)(((c * NPL + kd) * LR + kh) * LW);
    }
    __syncthreads();

    const int lane = tid & 63;
    const int wid  = tid >> 6;

    // ---- stage x -> LDS bf16 (packed dword writes, pads zeroed by lanes 57-63)
    for (int row = wid; row < LROWS; row += 4) {
        const int base = rowg[row];
        unsigned short* dst = &xl[row * LW];
        if (lane < 57) {
            float v0 = 0.0f, v1 = 0.0f;
            const int w0 = 2 * lane - 1;          // win for slot 2*lane+2
            if (base >= 0) {
                if (lane >= 1)  v0 = x[base + w0];
                if (lane <= 55) v1 = x[base + w0 + 1];
            }
            unsigned pk;
            asm("v_cvt_pk_bf16_f32 %0, %1, %2" : "=v"(pk) : "v"(v0), "v"(v1));
            *reinterpret_cast<unsigned*>(&dst[2 * lane + 2]) = pk;  // slots 2l+2,2l+3
        } else {
            const int dw = (lane == 57) ? 0 : lane;  // dwords {0, 58..63}
            *reinterpret_cast<unsigned*>(&dst[2 * dw]) = 0u;
        }
    }
    __syncthreads();

    // ---- per-wave geometry: wave = (waveN spatial half) x (ddl dd of pair)
    const int waveN = wid & 1;
    const int ddl   = wid >> 1;
    const int l15   = lane & 15;
    const int kgrp  = lane >> 4;
    const int ddoff = ddl * (LR * LW);   // +1 plane per dd_local

    int bidx[NF];
    #pragma unroll
    for (int f = 0; f < NF; ++f) {
        const int sp  = waveN * 112 + f * 16 + l15;
        const int hoL = sp / 56;
        const int wo  = sp - hoL * 56;
        bidx[f] = hoL * 2 * LW + 2 * wo;
    }

    // ---- acc init with bias: co = a*16 + kgrp*4 + r
    f32x4 acc[4][NF];
    #pragma unroll
    for (int a = 0; a < 4; ++a) {
        f32x4 bv;
        #pragma unroll
        for (int r = 0; r < 4; ++r) bv[r] = bias[a * 16 + kgrp * 4 + r];
        #pragma unroll
        for (int f = 0; f < NF; ++f) acc[a][f] = bv;
    }

    // ---- K loop: double-buffered A frags, barrier-free
    const short8* wb = wbuf + lane;
    short8 Acur[4], Anxt[4];
    #pragma unroll
    for (int a = 0; a < 4; ++a) Acur[a] = wb[a * 64];

    for (int ch = 0; ch < NCH; ++ch) {
        if (ch + 1 < NCH) {
            #pragma unroll
            for (int a = 0; a < 4; ++a) Anxt[a] = wb[((ch + 1) * 4 + a) * 64];
        }
        const int tb = (int)tabr[ch * 4 + kgrp] + ddoff;
        #pragma unroll
        for (int f = 0; f < NF; ++f) {
            const unsigned* p = reinterpret_cast<const unsigned*>(&xl[tb + bidx[f]]);
            union { unsigned u[4]; short8 s; } bx;
            bx.u[0] = p[0]; bx.u[1] = p[1]; bx.u[2] = p[2]; bx.u[3] = p[3];
            acc[0][f] = __builtin_amdgcn_mfma_f32_16x16x32_bf16(Acur[0], bx.s, acc[0][f], 0, 0, 0);
            acc[1][f] = __builtin_amdgcn_mfma_f32_16x16x32_bf16(Acur[1], bx.s, acc[1][f], 0, 0, 0);
            acc[2][f] = __builtin_amdgcn_mfma_f32_16x16x32_bf16(Acur[2], bx.s, acc[2][f], 0, 0, 0);
            acc[3][f] = __builtin_amdgcn_mfma_f32_16x16x32_bf16(Acur[3], bx.s, acc[3][f], 0, 0, 0);
        }
        #pragma unroll
        for (int a = 0; a < 4; ++a) Acur[a] = Anxt[a];
    }

    // ---- store
    const int dd = dd0 + ddl;
    #pragma unroll
    for (int f = 0; f < NF; ++f) {
        const int sp  = waveN * 112 + f * 16 + l15;
        const int hoL = sp / 56;
        const int wo  = sp - hoL * 56;
        const int ho  = ho0 + hoL;
        float* op = out + (((size_t)(n * CO) * DO_ + dd) * HO + ho) * WO + wo;
        #pragma unroll
        for (int a = 0; a < 4; ++a) {
            const int co = a * 16 + kgrp * 4;
            #pragma unroll
            for (int r = 0; r < 4; ++r)
                op[(size_t)(co + r) * DHWO] = acc[a][f][r];
        }
    }
}

extern "C" void kernel_launch(void* const* d_in, const int* in_sizes, int n_in,
                              void* d_out, int out_size, void* d_ws, size_t ws_size,
                              hipStream_t stream) {
    const float* x    = (const float*)d_in[0];
    const float* wgt  = (const float*)d_in[1];
    const float* bias = (const float*)d_in[2];
    float* out        = (float*)d_out;
    short8* wbuf      = (short8*)d_ws;   // 27*4*64*16 = 110592 B

    hipLaunchKernelGGL(prep_weights, dim3(NCH * 4, 1, 1), dim3(64, 1, 1), 0, stream,
                       wgt, wbuf);

    // grid: 8 n * 8 dd-pairs * 14 ho-tiles = 896 blocks
    dim3 grid(8 * 8 * 14, 1, 1);
    hipLaunchKernelGGL(conv3d_mfma3, grid, dim3(256, 1, 1), 0, stream,
                       x, wbuf, bias, out);
}

// Round 5
// 77.242 us; speedup vs baseline: 198.9319x; 1.1912x over previous
//
#include <hip/hip_runtime.h>

// Conv3D implicit GEMM, round 5: 512-thr blocks (8 waves = 2dd x 4ho),
// wave = 64co x 64wo (padded), LWS=144 bank-skewed LDS rows, ds_read2-friendly
// B-frags, double-buffered A-frags. ~14 waves/CU target.
// x (8,3,16,112,112) f32, w (64,3,5,7,7), bias (64,) -> out (8,64,16,56,56) f32

typedef __attribute__((ext_vector_type(8))) short short8;
typedef __attribute__((ext_vector_type(4))) float f32x4;

#define CI 3
#define DI 16
#define HI 112
#define WI 112
#define CO 64
#define DO_ 16
#define HO 56
#define WO 56
#define HW_IN 12544
#define DHWO 50176

#define NROW 105            // (c,kd,kh) rows
#define NROWP 108
#define NCH 27
#define TH 4                // ho rows per block
#define NPL 6               // staged d-planes per c (KD + TD - 1), TD=2
#define LR 13               // staged h-rows per plane (2*TH + KH - 2)
#define LROWS (CI*NPL*LR)   // 234
#define LWS 144             // shorts per staged row; 72 dwords -> +8 bank skew/row
#define XLSZ (LROWS*LWS)    // 33696 shorts

__device__ __forceinline__ unsigned short f2bf(float f) {
    unsigned u = __float_as_uint(f);
    return (unsigned short)((u + 0x7FFFu + ((u >> 16) & 1u)) >> 16);
}

// weights -> fragment-ready bf16: wbuf[(ch*4+a)*64 + lane] = short8,
// element j: co = a*16 + (lane&15), row r = ch*4 + (lane>>4) -> (c,kd,kh), kw = j.
__global__ void prep_weights(const float* __restrict__ wgt, short8* __restrict__ wbuf) {
    const int t    = blockIdx.x * 64 + threadIdx.x;   // 27*4*64 = 6912
    const int lane = t & 63;
    const int cf   = t >> 6;
    const int ch   = cf >> 2;
    const int a    = cf & 3;
    const int l15  = lane & 15;
    const int kgrp = lane >> 4;
    const int co   = a * 16 + l15;
    const int r    = ch * 4 + kgrp;
    const int rc   = (r < NROW) ? r : (NROW - 1);
    const int c    = rc / 35;
    const int kd   = (rc / 7) % 5;
    const int kh   = rc % 7;
    const float* wsrc = wgt + (((co * CI + c) * 5 + kd) * 7 + kh) * 7;
    short8 v;
    #pragma unroll
    for (int j = 0; j < 8; ++j) {
        float w = (r < NROW && j < 7) ? wsrc[j] : 0.0f;
        v[j] = (short)f2bf(w);
    }
    wbuf[(size_t)cf * 64 + lane] = v;
}

__launch_bounds__(512, 2)
__global__ void conv3d_mfma4(const float* __restrict__ x,
                             const short8* __restrict__ wbuf,
                             const float* __restrict__ bias,
                             float* __restrict__ out) {
    __shared__ unsigned short xl[XLSZ];     // 67392 B
    __shared__ int rowg[LROWS];
    __shared__ unsigned short tabr[NROWP];

    const int tid = threadIdx.x;
    int b = blockIdx.x;
    const int ht  = b % 14;  b /= 14;
    const int ddp = b % 8;
    const int n   = b / 8;
    const int ho0 = ht * TH;
    const int dd0 = ddp * 2;

    // per-row global bases; plane p covers din = dd0 - 2 + p
    if (tid < LROWS) {
        const int c   = tid / (NPL * LR);
        const int rem = tid - c * (NPL * LR);
        const int p   = rem / LR;
        const int rl  = rem - p * LR;
        const int din = dd0 - 2 + p;
        const int hin = 2 * ho0 - 3 + rl;
        const bool ok = ((unsigned)din < (unsigned)DI) && ((unsigned)hin < (unsigned)HI);
        rowg[tid] = ok ? ((n * CI + c) * DI + din) * HW_IN + hin * WI : -1;
    }
    // chunk-row -> LDS short-index base (ddl = 0, hoL = 0)
    if (tid < NROWP) {
        const int rc = (tid < NROW) ? tid : (NROW - 1);
        const int c  = rc / 35;
        const int kd = (rc / 7) % 5;
        const int kh = rc % 7;
        tabr[tid] = (unsigned short)(((c * NPL + kd) * LR + kh) * LWS);
    }
    __syncthreads();

    const int lane = tid & 63;
    const int wid  = tid >> 6;          // 0..7

    // ---- stage x -> LDS bf16 (packed dword writes; slot s holds win = s-3)
    for (int row = wid; row < LROWS; row += 8) {
        const int base = rowg[row];
        unsigned short* dst = &xl[row * LWS];
        if (lane < 57) {
            float v0 = 0.0f, v1 = 0.0f;
            const int w0 = 2 * lane - 1;          // win for slot 2*lane+2
            if (base >= 0) {
                if (lane >= 1)  v0 = x[base + w0];
                if (lane <= 55) v1 = x[base + w0 + 1];
            }
            unsigned pk;
            asm("v_cvt_pk_bf16_f32 %0, %1, %2" : "=v"(pk) : "v"(v0), "v"(v1));
            *reinterpret_cast<unsigned*>(&dst[2 * lane + 2]) = pk;
        } else {
            const int dw = (lane == 57) ? 0 : lane;   // dwords {0, 58..63}
            *reinterpret_cast<unsigned*>(&dst[2 * dw]) = 0u;
        }
    }
    __syncthreads();

    // ---- wave roles: 2 ddl x 4 hoL; wave = 64 co x 64 wo
    const int ddl  = wid & 1;
    const int hoL  = wid >> 1;
    const int l15  = lane & 15;
    const int kgrp = lane >> 4;
    const int woff = ddl * (LR * LWS) + hoL * (2 * LWS);   // shorts

    // acc init with bias: co = a*16 + kgrp*4 + r
    f32x4 acc[4][4];
    #pragma unroll
    for (int a = 0; a < 4; ++a) {
        f32x4 bv;
        #pragma unroll
        for (int r = 0; r < 4; ++r) bv[r] = bias[a * 16 + kgrp * 4 + r];
        #pragma unroll
        for (int f = 0; f < 4; ++f) acc[a][f] = bv;
    }

    // ---- K loop: double-buffered A frags + prefetched row base
    const short8* wbp = wbuf + lane;
    short8 Acur[4], Anxt[4];
    #pragma unroll
    for (int a = 0; a < 4; ++a) Acur[a] = wbp[a * 64];
    int tb = (int)tabr[kgrp] + woff;

    const unsigned* xlu = reinterpret_cast<const unsigned*>(xl);

    for (int ch = 0; ch < NCH; ++ch) {
        int tbn = 0;
        if (ch + 1 < NCH) {
            tbn = (int)tabr[(ch + 1) * 4 + kgrp] + woff;
            #pragma unroll
            for (int a = 0; a < 4; ++a) Anxt[a] = wbp[((ch + 1) * 4 + a) * 64];
        }
        const unsigned* xp = xlu + (tb >> 1) + l15;   // dword index
        union { unsigned u[4]; short8 s; } bx[4];
        #pragma unroll
        for (int f = 0; f < 4; ++f) {
            const unsigned* p = xp + f * 16;
            bx[f].u[0] = p[0]; bx[f].u[1] = p[1];
            bx[f].u[2] = p[2]; bx[f].u[3] = p[3];
        }
        #pragma unroll
        for (int f = 0; f < 4; ++f) {
            acc[0][f] = __builtin_amdgcn_mfma_f32_16x16x32_bf16(Acur[0], bx[f].s, acc[0][f], 0, 0, 0);
            acc[1][f] = __builtin_amdgcn_mfma_f32_16x16x32_bf16(Acur[1], bx[f].s, acc[1][f], 0, 0, 0);
            acc[2][f] = __builtin_amdgcn_mfma_f32_16x16x32_bf16(Acur[2], bx[f].s, acc[2][f], 0, 0, 0);
            acc[3][f] = __builtin_amdgcn_mfma_f32_16x16x32_bf16(Acur[3], bx[f].s, acc[3][f], 0, 0, 0);
        }
        tb = tbn;
        #pragma unroll
        for (int a = 0; a < 4; ++a) Acur[a] = Anxt[a];
    }

    // ---- store (mask dead cols wo >= 56)
    const int dd = dd0 + ddl;
    const int ho = ho0 + hoL;
    #pragma unroll
    for (int f = 0; f < 4; ++f) {
        const int wo = f * 16 + l15;
        if (f < 3 || l15 < 8) {
            float* op = out + (((size_t)(n * CO) * DO_ + dd) * HO + ho) * WO + wo;
            #pragma unroll
            for (int a = 0; a < 4; ++a) {
                const int co = a * 16 + kgrp * 4;
                #pragma unroll
                for (int r = 0; r < 4; ++r)
                    op[(size_t)(co + r) * DHWO] = acc[a][f][r];
            }
        }
    }
}

extern "C" void kernel_launch(void* const* d_in, const int* in_sizes, int n_in,
                              void* d_out, int out_size, void* d_ws, size_t ws_size,
                              hipStream_t stream) {
    const float* x    = (const float*)d_in[0];
    const float* wgt  = (const float*)d_in[1];
    const float* bias = (const float*)d_in[2];
    float* out        = (float*)d_out;
    short8* wbuf      = (short8*)d_ws;   // 27*4*64*16 = 110592 B

    hipLaunchKernelGGL(prep_weights, dim3(NCH * 4, 1, 1), dim3(64, 1, 1), 0, stream,
                       wgt, wbuf);

    // grid: 8 n * 8 dd-pairs * 14 ho-tiles = 896 blocks of 512 threads
    dim3 grid(8 * 8 * 14, 1, 1);
    hipLaunchKernelGGL(conv3d_mfma4, grid, dim3(512, 1, 1), 0, stream,
                       x, wbuf, bias, out);
}